// Round 6
// baseline (288.848 us; speedup 1.0000x reference)
//
#include <hip/hip_runtime.h>
#include <math.h>

// Problem constants (b=8, c=2048, e=64, h=8)
#define NTOK 16384
#define EDIM 64
#define HHE  512   // h*e

// ---------------------------------------------------------------------------
// Kernel 1: q/k/v = x @ W^T + b   (M=16384, N=512 per matrix, K=64)  — REBUILT
// Register-resident W, ZERO LDS (R5 analysis: the LDS variant is DS-pipe
// bound at ~46 µs because the DS pipe is per-CU shared by 4 SIMDs).
// Each wave owns one 64-col chunk of one W: lane n holds W[cc*64+n][0..63]
// in 64 VGPRs (loaded once, amortized over 64 tokens). x rows are
// wave-uniform -> scalar loads, consumed as the SGPR operand of v_fma.
// Inner loop: 64 fma + 1 coalesced 256B store per token. No barriers.
// ---------------------------------------------------------------------------
__global__ __launch_bounds__(256) void qkv_kernel(
    const float* __restrict__ x,
    const float* __restrict__ Wk, const float* __restrict__ bk,
    const float* __restrict__ Wq, const float* __restrict__ bq,
    const float* __restrict__ Wv, const float* __restrict__ bv,
    float* __restrict__ qb, float* __restrict__ kb, float* __restrict__ vb)
{
    const int lane = threadIdx.x & 63;
    const int w    = __builtin_amdgcn_readfirstlane(threadIdx.x >> 6); // uniform
    const int z    = blockIdx.z;

    const int omega = blockIdx.x * 4 + w;     // wave id in [0, 2048)
    const int cc    = omega & 7;              // col chunk (x64)
    const int g     = omega >> 3;             // token group (x64), [0,256)

    const float* W; const float* bias; float* outp;
    if      (z == 0) { W = Wk; bias = bk; outp = kb; }
    else if (z == 1) { W = Wq; bias = bq; outp = qb; }
    else             { W = Wv; bias = bv; outp = vb; }

    // lane n's weight row: W[cc*64+n][0..63] -> 64 VGPRs (once per wave life)
    float wreg[64];
    {
        const float4* wr = (const float4*)(W + (size_t)(cc * 64 + lane) * EDIM);
        #pragma unroll
        for (int i = 0; i < 16; ++i) {
            const float4 v = wr[i];
            wreg[4 * i + 0] = v.x;
            wreg[4 * i + 1] = v.y;
            wreg[4 * i + 2] = v.z;
            wreg[4 * i + 3] = v.w;
        }
    }
    const float bn = bias[cc * 64 + lane];

    for (int t = 0; t < 64; ++t) {
        const int tok = g * 64 + t;
        const float* __restrict__ xrow = x + (size_t)tok * EDIM;  // uniform addr
        // 4 accumulators: chains 16 deep (64 cyc) < 128-cyc issue -> no stall
        float a0 = 0.0f, a1 = 0.0f, a2 = 0.0f, a3 = 0.0f;
        #pragma unroll
        for (int k = 0; k < 16; ++k) {
            a0 = fmaf(xrow[k     ], wreg[k     ], a0);
            a1 = fmaf(xrow[k + 16], wreg[k + 16], a1);
            a2 = fmaf(xrow[k + 32], wreg[k + 32], a2);
            a3 = fmaf(xrow[k + 48], wreg[k + 48], a3);
        }
        outp[(size_t)tok * HHE + cc * 64 + lane] = ((a0 + a1) + (a2 + a3)) + bn;
    }
}

// ---------------------------------------------------------------------------
// Kernel 2: per-token scores -> entmax_bisect -> att @ v
// Changes vs R5 (each analyzed against the R2 failure root cause):
//  * bisection test is `f >= 0` instead of `f*f_lo >= 0`: f_lo >= 0 always
//    (max elem contributes clamp(1)^2 = 1), so identical when f_lo > 0; when
//    f_lo == 0 (isolated max, one-hot row) this keeps tau at the EXACT root
//    and the normalized output is exactly one-hot = reference's output.
//    Also deletes the whole f_lo evaluation pass.
//  * 8 bisection + 3 GUARDED Newton steps: tau += max(f,0)/(2s). R2's bug
//    was the one-hot case walking tau above the root (f<0) and unguarded
//    Newton jumping down by ~f/(2s) ~ -3.7. max(f,0) provably never moves
//    on the f<0 side; on the f>=0 side Newton on the convex decreasing f
//    (z<=1 for all elems once tau >= mx-1) is monotone from below:
//    e' <= 32 e^2 -> after 8 bisect (e=3.4e-3) 3 steps give e ~ 6e-10.
//    s >= mx - tau >= 1/8 at all times, so no div-by-0 (epsilon for fp).
//  * normalization folded into the av epilogue (8 muls instead of 64).
// ---------------------------------------------------------------------------
__device__ __forceinline__ float clamp01(float z) {
    return __builtin_amdgcn_fmed3f(z, 0.0f, 1.0f);   // v_med3_f32
}
__device__ __forceinline__ float pgen(float z, float inv) {
    return z > 0.0f ? exp2f(inv * log2f(fmaxf(z, 1e-30f))) : 0.0f;
}

__global__ __launch_bounds__(256) void attn_kernel(
    float* qb,                    // read q, then write res (alias)
    const float* kb, const float* vb,
    const float* alpha_p)
{
    __shared__ float sK[4][HHE];
    __shared__ float sV[4][HHE];
    const int lane = threadIdx.x & 63;
    const int w    = threadIdx.x >> 6;
    const int tok  = blockIdx.x * 4 + w;

    const float alpha = alpha_p[0];
    const float am1   = alpha - 1.0f;

    float qr[8];
    {
        const float* qp = qb + (size_t)tok * HHE;
        const float* kp = kb + (size_t)tok * HHE;
        const float* vp = vb + (size_t)tok * HHE;
        #pragma unroll
        for (int h = 0; h < 8; ++h) {
            qr[h]                 = qp[h * 64 + lane];   // lane i holds q[h][i]
            sK[w][h * 64 + lane]  = kp[h * 64 + lane];
            sV[w][h * 64 + lane]  = vp[h * 64 + lane];
        }
    }
    __syncthreads();

    // dot row: row[j] = sum_h q[h][lane] * k[h][j]
    float row[64];
    #pragma unroll
    for (int j = 0; j < 64; ++j) row[j] = 0.0f;
    #pragma unroll
    for (int h = 0; h < 8; ++h) {
        const float qh = qr[h];
        #pragma unroll
        for (int j4 = 0; j4 < 16; ++j4) {
            const float4 k4 = *(const float4*)&sK[w][h * 64 + j4 * 4]; // broadcast
            row[j4*4+0] = fmaf(qh, k4.x, row[j4*4+0]);
            row[j4*4+1] = fmaf(qh, k4.y, row[j4*4+1]);
            row[j4*4+2] = fmaf(qh, k4.z, row[j4*4+2]);
            row[j4*4+3] = fmaf(qh, k4.w, row[j4*4+3]);
        }
    }

    // Xa = dot/sqrt(e) * (alpha-1);  1/8 and am1 fold exactly (pow-of-2)
    const float scale = am1 * 0.125f;
    #pragma unroll
    for (int j = 0; j < 64; ++j) row[j] *= scale;

    float mx = row[0];
    #pragma unroll
    for (int j = 1; j < 64; ++j) mx = fmaxf(mx, row[j]);

    float tau_lo = mx - 1.0f;                         // _gp(1, alpha) = 1
    const float tau_hi = mx - exp2f(-6.0f * am1);     // (1/64)^am1
    float dm = tau_hi - tau_lo;
    float inv_sum;

    if (am1 == 0.5f) {
        // alpha = 1.5: p(z) = max(z,0)^2; z <= 1 always (tau >= mx-1),
        // so med3(z,0,1) == clamp == max(z,0) exactly.
        // 8 bisection steps with the f >= 0 test (see header comment).
        #pragma unroll
        for (int it = 0; it < 8; ++it) {
            dm *= 0.5f;
            const float tau_m = tau_lo + dm;
            float f0 = -1.0f, f1 = 0.0f, f2 = 0.0f, f3 = 0.0f;
            #pragma unroll
            for (int j = 0; j < 64; j += 4) {
                const float a0 = clamp01(row[j+0] - tau_m);
                const float a1 = clamp01(row[j+1] - tau_m);
                const float a2 = clamp01(row[j+2] - tau_m);
                const float a3 = clamp01(row[j+3] - tau_m);
                f0 = fmaf(a0, a0, f0); f1 = fmaf(a1, a1, f1);
                f2 = fmaf(a2, a2, f2); f3 = fmaf(a3, a3, f3);
            }
            const float f = (f0 + f1) + (f2 + f3);
            tau_lo = (f >= 0.0f) ? tau_m : tau_lo;
        }
        // 3 guarded Newton steps (monotone from below; no move if f < 0)
        float tau = tau_lo;
        #pragma unroll
        for (int it = 0; it < 3; ++it) {
            float f0 = -1.0f, f1 = 0.0f, f2 = 0.0f, f3 = 0.0f;
            float s0 = 0.0f, s1 = 0.0f, s2 = 0.0f, s3 = 0.0f;
            #pragma unroll
            for (int j = 0; j < 64; j += 4) {
                const float a0 = clamp01(row[j+0] - tau);
                const float a1 = clamp01(row[j+1] - tau);
                const float a2 = clamp01(row[j+2] - tau);
                const float a3 = clamp01(row[j+3] - tau);
                f0 = fmaf(a0, a0, f0); f1 = fmaf(a1, a1, f1);
                f2 = fmaf(a2, a2, f2); f3 = fmaf(a3, a3, f3);
                s0 += a0; s1 += a1; s2 += a2; s3 += a3;
            }
            const float f = (f0 + f1) + (f2 + f3);
            const float s = ((s0 + s1) + (s2 + s3)) + 1e-20f;  // s >= 1/8 anyway
            tau = tau + fmaxf(f, 0.0f) / (s + s);
        }
        // final p (unnormalized) + sum; normalization folded into av epilogue
        float s0 = 0.0f, s1 = 0.0f;
        #pragma unroll
        for (int j = 0; j < 64; j += 2) {
            float a0 = clamp01(row[j+0] - tau);
            float a1 = clamp01(row[j+1] - tau);
            a0 *= a0; a1 *= a1;
            row[j+0] = a0; row[j+1] = a1;
            s0 += a0; s1 += a1;
        }
        inv_sum = 1.0f / (s0 + s1);
    } else {
        // faithful general-alpha path (unused for this problem's alpha=1.5)
        const float inv = 1.0f / am1;
        float tau_m = tau_lo;
        float f_lo = -1.0f;
        #pragma unroll
        for (int j = 0; j < 64; ++j) f_lo += pgen(row[j] - tau_lo, inv);
        for (int it = 0; it < 30; ++it) {
            dm *= 0.5f;
            tau_m = tau_lo + dm;
            float f = -1.0f;
            #pragma unroll
            for (int j = 0; j < 64; ++j) f += pgen(row[j] - tau_m, inv);
            tau_lo = (f * f_lo >= 0.0f) ? tau_m : tau_lo;
        }
        float s = 0.0f;
        #pragma unroll
        for (int j = 0; j < 64; ++j) {
            const float pm = pgen(row[j] - tau_m, inv);
            row[j] = pm;
            s += pm;
        }
        inv_sum = 1.0f / s;
    }

    // res[h][lane] = inv_sum * sum_j p[lane][j] * v[h][j]
    float acc[8];
    #pragma unroll
    for (int h = 0; h < 8; ++h) acc[h] = 0.0f;
    #pragma unroll
    for (int h = 0; h < 8; ++h) {
        #pragma unroll
        for (int j4 = 0; j4 < 16; ++j4) {
            const float4 v4 = *(const float4*)&sV[w][h * 64 + j4 * 4]; // broadcast
            acc[h] = fmaf(row[j4*4+0], v4.x, acc[h]);
            acc[h] = fmaf(row[j4*4+1], v4.y, acc[h]);
            acc[h] = fmaf(row[j4*4+2], v4.z, acc[h]);
            acc[h] = fmaf(row[j4*4+3], v4.w, acc[h]);
        }
    }
    float* rp = qb + (size_t)tok * HHE;   // res overwrites q (safe: own wave only)
    #pragma unroll
    for (int h = 0; h < 8; ++h) rp[h * 64 + lane] = acc[h] * inv_sum;
}

// ---------------------------------------------------------------------------
// Kernel 3: out = res @ Wu^T + bu   (M=16384, N=64, K=512)
// R5 version, unchanged (k-outer LDS GEMM, conflict-free). Held constant.
// ---------------------------------------------------------------------------
__global__ __launch_bounds__(256) void out_kernel(
    const float* __restrict__ resb, const float* __restrict__ Wu,
    const float* __restrict__ bu, float* __restrict__ out)
{
    __shared__ float rT[64 * 68];        // [kk][tok]  17.4 KB
    __shared__ float wT[64 * 68];        // [kk][m]    17.4 KB

    const int tid  = threadIdx.x;
    const int tok0 = blockIdx.x * 64;

    const int t    = tid >> 2;           // 0..63 (staging: token row / Wu row)
    const int kq2  = tid & 3;            // 0..3
    const int tokq = tid >> 4;           // 0..15 (compute: 4-token group)
    const int mq   = tid & 15;           // 0..15 (compute: 4-col group)

    float acc[4][4];
    #pragma unroll
    for (int a = 0; a < 4; ++a)
        #pragma unroll
        for (int b = 0; b < 4; ++b) acc[a][b] = 0.0f;

    const float4* rg = (const float4*)(resb + (size_t)(tok0 + t) * HHE);
    const float4* wg = (const float4*)(Wu   + (size_t)t * HHE);

    for (int kc = 0; kc < 8; ++kc) {
        // ---- stage res & Wu chunks transposed into LDS
        #pragma unroll
        for (int rep = 0; rep < 4; ++rep) {
            const int kq = rep * 4 + kq2;            // 0..15 within chunk
            const float4 rv = rg[kc * 16 + kq];
            rT[(kq * 4 + 0) * 68 + t] = rv.x;
            rT[(kq * 4 + 1) * 68 + t] = rv.y;
            rT[(kq * 4 + 2) * 68 + t] = rv.z;
            rT[(kq * 4 + 3) * 68 + t] = rv.w;
            const float4 wv = wg[kc * 16 + kq];
            wT[(kq * 4 + 0) * 68 + t] = wv.x;
            wT[(kq * 4 + 1) * 68 + t] = wv.y;
            wT[(kq * 4 + 2) * 68 + t] = wv.z;
            wT[(kq * 4 + 3) * 68 + t] = wv.w;
        }
        __syncthreads();

        // ---- compute: per kk, 2 x ds_read_b128 + 16 fma
        #pragma unroll 4
        for (int kk = 0; kk < 64; ++kk) {
            const float4 a4 = *(const float4*)&rT[kk * 68 + tokq * 4];
            const float4 b4 = *(const float4*)&wT[kk * 68 + mq * 4];
            const float ar[4] = {a4.x, a4.y, a4.z, a4.w};
            const float br[4] = {b4.x, b4.y, b4.z, b4.w};
            #pragma unroll
            for (int a = 0; a < 4; ++a)
                #pragma unroll
                for (int b = 0; b < 4; ++b)
                    acc[a][b] = fmaf(ar[a], br[b], acc[a][b]);
        }
        __syncthreads();                 // LDS reused next chunk
    }

    const float4 b4 = ((const float4*)bu)[mq];
    #pragma unroll
    for (int a = 0; a < 4; ++a) {
        float4 o;
        o.x = acc[a][0] + b4.x;
        o.y = acc[a][1] + b4.y;
        o.z = acc[a][2] + b4.z;
        o.w = acc[a][3] + b4.w;
        *(float4*)&out[(size_t)(tok0 + tokq * 4 + a) * 64 + mq * 4] = o;
    }
}

// ---------------------------------------------------------------------------
extern "C" void kernel_launch(void* const* d_in, const int* in_sizes, int n_in,
                              void* d_out, int out_size, void* d_ws, size_t ws_size,
                              hipStream_t stream)
{
    const float* x     = (const float*)d_in[0];
    const float* alpha = (const float*)d_in[1];
    const float* Wk    = (const float*)d_in[2];
    const float* bk    = (const float*)d_in[3];
    const float* Wq    = (const float*)d_in[4];
    const float* bq    = (const float*)d_in[5];
    const float* Wv    = (const float*)d_in[6];
    const float* bv    = (const float*)d_in[7];
    const float* Wu    = (const float*)d_in[8];
    const float* bu    = (const float*)d_in[9];
    float* out = (float*)d_out;

    float* ws = (float*)d_ws;
    float* qb = ws;                                  // res aliases q
    float* kb = ws + (size_t)NTOK * HHE;
    float* vb = ws + 2 * (size_t)NTOK * HHE;         // total 96 MB

    qkv_kernel<<<dim3(512, 1, 3), 256, 0, stream>>>(
        x, Wk, bk, Wq, bq, Wv, bv, qb, kb, vb);
    attn_kernel<<<NTOK / 4, 256, 0, stream>>>(qb, kb, vb, alpha);
    out_kernel<<<NTOK / 64, 256, 0, stream>>>(qb, Wu, bu, out);
}

// Round 7
// 228.851 us; speedup vs baseline: 1.2622x; 1.2622x over previous
//
#include <hip/hip_runtime.h>
#include <math.h>

// Problem constants (b=8, c=2048, e=64, h=8)
#define NTOK 16384
#define EDIM 64
#define HHE  512   // h*e

typedef _Float16 half8 __attribute__((ext_vector_type(8)));
typedef float    floatx4 __attribute__((ext_vector_type(4)));

__device__ __forceinline__ half8 cvt8(const float4 a, const float4 b) {
    half8 h;
    h[0] = (_Float16)a.x; h[1] = (_Float16)a.y;
    h[2] = (_Float16)a.z; h[3] = (_Float16)a.w;
    h[4] = (_Float16)b.x; h[5] = (_Float16)b.y;
    h[6] = (_Float16)b.z; h[7] = (_Float16)b.w;
    return h;
}

// ---------------------------------------------------------------------------
// Kernel 1: q/k/v = x @ W^T + b   (M=16384, N=512 per matrix, K=64) — MFMA
// fp16-input mfma_f32_16x16x32_f16 (fp32 accumulate). Both x and W are
// row-major in K, the m97 gemm_bt symmetric case:
//   A-frag: A[m = lane&15][k = (lane>>4)*8 + j]   (HW-verified, m120)
//   B-frag: B[n = lane&15][k = (lane>>4)*8 + j]   (same load pattern from W)
//   C/D:    col = lane&15, row = (lane>>4)*4 + reg (HW-verified, m89/m91)
// Wave = 16 tok x 128 col (8 tiles, A-frag reused 8x). K=64 -> 2 mfma/tile.
// Zero LDS, zero barriers; x/W fragment loads are L2-hot gathers.
// fp16 rounding error ~5e-4 rms in q/k/v -> ~1e-2 worst-case in out,
// vs 4.28e-2 threshold (MFMA products/accum are fp32 — input rounding only).
// ---------------------------------------------------------------------------
__global__ __launch_bounds__(256) void qkv_kernel(
    const float* __restrict__ x,
    const float* __restrict__ Wk, const float* __restrict__ bk,
    const float* __restrict__ Wq, const float* __restrict__ bq,
    const float* __restrict__ Wv, const float* __restrict__ bv,
    float* __restrict__ qb, float* __restrict__ kb, float* __restrict__ vb)
{
    const int tid  = threadIdx.x;
    const int lane = tid & 63;
    const int wv   = tid >> 6;             // wave 0..3
    const int z    = blockIdx.z;

    const float* W; const float* bias; float* outp;
    if      (z == 0) { W = Wk; bias = bk; outp = kb; }
    else if (z == 1) { W = Wq; bias = bq; outp = qb; }
    else             { W = Wv; bias = bv; outp = vb; }

    const int tok0 = blockIdx.x * 64 + wv * 16;   // this wave's 16 tokens
    const int col0 = blockIdx.y * 128;            // this block's 128 cols

    const int m    = lane & 15;            // A row (tok) / B row (col) / C col
    const int quad = lane >> 4;            // k-quad: k = quad*8 + j

    floatx4 acc[8];
    #pragma unroll
    for (int ct = 0; ct < 8; ++ct) acc[ct] = (floatx4){0.f, 0.f, 0.f, 0.f};

    const float* xrow = x + (size_t)(tok0 + m) * EDIM + quad * 8;

    #pragma unroll
    for (int kc = 0; kc < 2; ++kc) {       // K=64 in two 32-chunks
        const float4 xa = *(const float4*)(xrow + kc * 32);
        const float4 xb = *(const float4*)(xrow + kc * 32 + 4);
        const half8 af = cvt8(xa, xb);
        #pragma unroll
        for (int ct = 0; ct < 8; ++ct) {
            const float* wrow =
                W + (size_t)(col0 + ct * 16 + m) * EDIM + quad * 8 + kc * 32;
            const float4 wa = *(const float4*)(wrow);
            const float4 wb = *(const float4*)(wrow + 4);
            const half8 bf = cvt8(wa, wb);
            acc[ct] = __builtin_amdgcn_mfma_f32_16x16x32_f16(af, bf, acc[ct], 0, 0, 0);
        }
    }

    // epilogue: bias + store. C/D: col = m, row = quad*4 + r.
    #pragma unroll
    for (int ct = 0; ct < 8; ++ct) {
        const int col = col0 + ct * 16 + m;
        const float bn = bias[col];
        #pragma unroll
        for (int r = 0; r < 4; ++r) {
            const int tok = tok0 + quad * 4 + r;
            outp[(size_t)tok * HHE + col] = acc[ct][r] + bn;
        }
    }
}

// ---------------------------------------------------------------------------
// Kernel 2: per-token scores -> entmax_bisect -> att @ v
// R6 version, unchanged (f>=0 bisection + guarded Newton). Held constant.
// ---------------------------------------------------------------------------
__device__ __forceinline__ float clamp01(float z) {
    return __builtin_amdgcn_fmed3f(z, 0.0f, 1.0f);   // v_med3_f32
}
__device__ __forceinline__ float pgen(float z, float inv) {
    return z > 0.0f ? exp2f(inv * log2f(fmaxf(z, 1e-30f))) : 0.0f;
}

__global__ __launch_bounds__(256) void attn_kernel(
    float* qb,                    // read q, then write res (alias)
    const float* kb, const float* vb,
    const float* alpha_p)
{
    __shared__ float sK[4][HHE];
    __shared__ float sV[4][HHE];
    const int lane = threadIdx.x & 63;
    const int w    = threadIdx.x >> 6;
    const int tok  = blockIdx.x * 4 + w;

    const float alpha = alpha_p[0];
    const float am1   = alpha - 1.0f;

    float qr[8];
    {
        const float* qp = qb + (size_t)tok * HHE;
        const float* kp = kb + (size_t)tok * HHE;
        const float* vp = vb + (size_t)tok * HHE;
        #pragma unroll
        for (int h = 0; h < 8; ++h) {
            qr[h]                 = qp[h * 64 + lane];   // lane i holds q[h][i]
            sK[w][h * 64 + lane]  = kp[h * 64 + lane];
            sV[w][h * 64 + lane]  = vp[h * 64 + lane];
        }
    }
    __syncthreads();

    // dot row: row[j] = sum_h q[h][lane] * k[h][j]
    float row[64];
    #pragma unroll
    for (int j = 0; j < 64; ++j) row[j] = 0.0f;
    #pragma unroll
    for (int h = 0; h < 8; ++h) {
        const float qh = qr[h];
        #pragma unroll
        for (int j4 = 0; j4 < 16; ++j4) {
            const float4 k4 = *(const float4*)&sK[w][h * 64 + j4 * 4]; // broadcast
            row[j4*4+0] = fmaf(qh, k4.x, row[j4*4+0]);
            row[j4*4+1] = fmaf(qh, k4.y, row[j4*4+1]);
            row[j4*4+2] = fmaf(qh, k4.z, row[j4*4+2]);
            row[j4*4+3] = fmaf(qh, k4.w, row[j4*4+3]);
        }
    }

    // Xa = dot/sqrt(e) * (alpha-1);  1/8 and am1 fold exactly (pow-of-2)
    const float scale = am1 * 0.125f;
    #pragma unroll
    for (int j = 0; j < 64; ++j) row[j] *= scale;

    float mx = row[0];
    #pragma unroll
    for (int j = 1; j < 64; ++j) mx = fmaxf(mx, row[j]);

    float tau_lo = mx - 1.0f;                         // _gp(1, alpha) = 1
    const float tau_hi = mx - exp2f(-6.0f * am1);     // (1/64)^am1
    float dm = tau_hi - tau_lo;
    float inv_sum;

    if (am1 == 0.5f) {
        // alpha = 1.5: p(z) = max(z,0)^2; z <= 1 always (tau >= mx-1).
        // 8 bisection steps, f >= 0 test (f_lo >= 0 provably; one-hot-safe).
        #pragma unroll
        for (int it = 0; it < 8; ++it) {
            dm *= 0.5f;
            const float tau_m = tau_lo + dm;
            float f0 = -1.0f, f1 = 0.0f, f2 = 0.0f, f3 = 0.0f;
            #pragma unroll
            for (int j = 0; j < 64; j += 4) {
                const float a0 = clamp01(row[j+0] - tau_m);
                const float a1 = clamp01(row[j+1] - tau_m);
                const float a2 = clamp01(row[j+2] - tau_m);
                const float a3 = clamp01(row[j+3] - tau_m);
                f0 = fmaf(a0, a0, f0); f1 = fmaf(a1, a1, f1);
                f2 = fmaf(a2, a2, f2); f3 = fmaf(a3, a3, f3);
            }
            const float f = (f0 + f1) + (f2 + f3);
            tau_lo = (f >= 0.0f) ? tau_m : tau_lo;
        }
        // 3 guarded Newton steps (tau += max(f,0)/(2s); never moves if f<0)
        float tau = tau_lo;
        #pragma unroll
        for (int it = 0; it < 3; ++it) {
            float f0 = -1.0f, f1 = 0.0f, f2 = 0.0f, f3 = 0.0f;
            float s0 = 0.0f, s1 = 0.0f, s2 = 0.0f, s3 = 0.0f;
            #pragma unroll
            for (int j = 0; j < 64; j += 4) {
                const float a0 = clamp01(row[j+0] - tau);
                const float a1 = clamp01(row[j+1] - tau);
                const float a2 = clamp01(row[j+2] - tau);
                const float a3 = clamp01(row[j+3] - tau);
                f0 = fmaf(a0, a0, f0); f1 = fmaf(a1, a1, f1);
                f2 = fmaf(a2, a2, f2); f3 = fmaf(a3, a3, f3);
                s0 += a0; s1 += a1; s2 += a2; s3 += a3;
            }
            const float f = (f0 + f1) + (f2 + f3);
            const float s = ((s0 + s1) + (s2 + s3)) + 1e-20f;  // s >= 1/8 anyway
            tau = tau + fmaxf(f, 0.0f) / (s + s);
        }
        // final p (unnormalized) + sum; normalization folded into av epilogue
        float s0 = 0.0f, s1 = 0.0f;
        #pragma unroll
        for (int j = 0; j < 64; j += 2) {
            float a0 = clamp01(row[j+0] - tau);
            float a1 = clamp01(row[j+1] - tau);
            a0 *= a0; a1 *= a1;
            row[j+0] = a0; row[j+1] = a1;
            s0 += a0; s1 += a1;
        }
        inv_sum = 1.0f / (s0 + s1);
    } else {
        // faithful general-alpha path (unused for this problem's alpha=1.5)
        const float inv = 1.0f / am1;
        float tau_m = tau_lo;
        float f_lo = -1.0f;
        #pragma unroll
        for (int j = 0; j < 64; ++j) f_lo += pgen(row[j] - tau_lo, inv);
        for (int it = 0; it < 30; ++it) {
            dm *= 0.5f;
            tau_m = tau_lo + dm;
            float f = -1.0f;
            #pragma unroll
            for (int j = 0; j < 64; ++j) f += pgen(row[j] - tau_m, inv);
            tau_lo = (f * f_lo >= 0.0f) ? tau_m : tau_lo;
        }
        float s = 0.0f;
        #pragma unroll
        for (int j = 0; j < 64; ++j) {
            const float pm = pgen(row[j] - tau_m, inv);
            row[j] = pm;
            s += pm;
        }
        inv_sum = 1.0f / s;
    }

    // res[h][lane] = inv_sum * sum_j p[lane][j] * v[h][j]
    float acc[8];
    #pragma unroll
    for (int h = 0; h < 8; ++h) acc[h] = 0.0f;
    #pragma unroll
    for (int h = 0; h < 8; ++h) {
        #pragma unroll
        for (int j4 = 0; j4 < 16; ++j4) {
            const float4 v4 = *(const float4*)&sV[w][h * 64 + j4 * 4]; // broadcast
            acc[h] = fmaf(row[j4*4+0], v4.x, acc[h]);
            acc[h] = fmaf(row[j4*4+1], v4.y, acc[h]);
            acc[h] = fmaf(row[j4*4+2], v4.z, acc[h]);
            acc[h] = fmaf(row[j4*4+3], v4.w, acc[h]);
        }
    }
    float* rp = qb + (size_t)tok * HHE;   // res overwrites q (safe: own wave only)
    #pragma unroll
    for (int h = 0; h < 8; ++h) rp[h * 64 + lane] = acc[h] * inv_sum;
}

// ---------------------------------------------------------------------------
// Kernel 3: out = res @ Wu^T + bu   (M=16384, N=64, K=512)
// R5 version, unchanged (k-outer LDS GEMM, conflict-free). Held constant.
// ---------------------------------------------------------------------------
__global__ __launch_bounds__(256) void out_kernel(
    const float* __restrict__ resb, const float* __restrict__ Wu,
    const float* __restrict__ bu, float* __restrict__ out)
{
    __shared__ float rT[64 * 68];        // [kk][tok]  17.4 KB
    __shared__ float wT[64 * 68];        // [kk][m]    17.4 KB

    const int tid  = threadIdx.x;
    const int tok0 = blockIdx.x * 64;

    const int t    = tid >> 2;           // 0..63 (staging: token row / Wu row)
    const int kq2  = tid & 3;            // 0..3
    const int tokq = tid >> 4;           // 0..15 (compute: 4-token group)
    const int mq   = tid & 15;           // 0..15 (compute: 4-col group)

    float acc[4][4];
    #pragma unroll
    for (int a = 0; a < 4; ++a)
        #pragma unroll
        for (int b = 0; b < 4; ++b) acc[a][b] = 0.0f;

    const float4* rg = (const float4*)(resb + (size_t)(tok0 + t) * HHE);
    const float4* wg = (const float4*)(Wu   + (size_t)t * HHE);

    for (int kc = 0; kc < 8; ++kc) {
        // ---- stage res & Wu chunks transposed into LDS
        #pragma unroll
        for (int rep = 0; rep < 4; ++rep) {
            const int kq = rep * 4 + kq2;            // 0..15 within chunk
            const float4 rv = rg[kc * 16 + kq];
            rT[(kq * 4 + 0) * 68 + t] = rv.x;
            rT[(kq * 4 + 1) * 68 + t] = rv.y;
            rT[(kq * 4 + 2) * 68 + t] = rv.z;
            rT[(kq * 4 + 3) * 68 + t] = rv.w;
            const float4 wv = wg[kc * 16 + kq];
            wT[(kq * 4 + 0) * 68 + t] = wv.x;
            wT[(kq * 4 + 1) * 68 + t] = wv.y;
            wT[(kq * 4 + 2) * 68 + t] = wv.z;
            wT[(kq * 4 + 3) * 68 + t] = wv.w;
        }
        __syncthreads();

        // ---- compute: per kk, 2 x ds_read_b128 + 16 fma
        #pragma unroll 4
        for (int kk = 0; kk < 64; ++kk) {
            const float4 a4 = *(const float4*)&rT[kk * 68 + tokq * 4];
            const float4 b4 = *(const float4*)&wT[kk * 68 + mq * 4];
            const float ar[4] = {a4.x, a4.y, a4.z, a4.w};
            const float br[4] = {b4.x, b4.y, b4.z, b4.w};
            #pragma unroll
            for (int a = 0; a < 4; ++a)
                #pragma unroll
                for (int b = 0; b < 4; ++b)
                    acc[a][b] = fmaf(ar[a], br[b], acc[a][b]);
        }
        __syncthreads();                 // LDS reused next chunk
    }

    const float4 b4 = ((const float4*)bu)[mq];
    #pragma unroll
    for (int a = 0; a < 4; ++a) {
        float4 o;
        o.x = acc[a][0] + b4.x;
        o.y = acc[a][1] + b4.y;
        o.z = acc[a][2] + b4.z;
        o.w = acc[a][3] + b4.w;
        *(float4*)&out[(size_t)(tok0 + tokq * 4 + a) * 64 + mq * 4] = o;
    }
}

// ---------------------------------------------------------------------------
extern "C" void kernel_launch(void* const* d_in, const int* in_sizes, int n_in,
                              void* d_out, int out_size, void* d_ws, size_t ws_size,
                              hipStream_t stream)
{
    const float* x     = (const float*)d_in[0];
    const float* alpha = (const float*)d_in[1];
    const float* Wk    = (const float*)d_in[2];
    const float* bk    = (const float*)d_in[3];
    const float* Wq    = (const float*)d_in[4];
    const float* bq    = (const float*)d_in[5];
    const float* Wv    = (const float*)d_in[6];
    const float* bv    = (const float*)d_in[7];
    const float* Wu    = (const float*)d_in[8];
    const float* bu    = (const float*)d_in[9];
    float* out = (float*)d_out;

    float* ws = (float*)d_ws;
    float* qb = ws;                                  // res aliases q
    float* kb = ws + (size_t)NTOK * HHE;
    float* vb = ws + 2 * (size_t)NTOK * HHE;         // total 96 MB

    qkv_kernel<<<dim3(NTOK / 64, 4, 3), 256, 0, stream>>>(
        x, Wk, bk, Wq, bq, Wv, bv, qb, kb, vb);
    attn_kernel<<<NTOK / 4, 256, 0, stream>>>(qb, kb, vb, alpha);
    out_kernel<<<NTOK / 64, 256, 0, stream>>>(qb, Wu, bu, out);
}